// Round 5
// baseline (203.428 us; speedup 1.0000x reference)
//
#include <hip/hip_runtime.h>
#include <math.h>

#define BB_   2
#define CIN_  256
#define NTOK_ 2048
#define FF_   512
#define COUT_ 256
#define NH_   8
#define DH_   64
#define HW_   128
#define BNEPS_ 1e-5f
#define SCALE_LOG2_ 0.09016844005556021f  /* log2(e)/16 */

typedef __attribute__((ext_vector_type(8))) short short8;
typedef __attribute__((ext_vector_type(4))) float f32x4;

__device__ inline unsigned short f2bf(float f) {
  union { float f; unsigned u; } v; v.f = f;
  unsigned r = (v.u + 0x7FFF + ((v.u >> 16) & 1)) >> 16;  // RNE
  return (unsigned short)r;
}
__device__ inline float bf2f(unsigned short u) {
  union { unsigned u; float f; } v; v.u = ((unsigned)u) << 16;
  return v.f;
}

// ---------------------------------------------------------------------------
// Kernel 0: prep — x fp32 [b][c][n] -> xT bf16 [b][n][c] (LDS transpose);
// weights fp32 -> bf16 flat; zero BN stats.
// ---------------------------------------------------------------------------
__global__ __launch_bounds__(256) void prep_kernel(
    const float* __restrict__ x, const float* __restrict__ WK,
    const float* __restrict__ WQ, const float* __restrict__ WV,
    const float* __restrict__ Wo, unsigned short* __restrict__ xT,
    unsigned short* __restrict__ Wkb, unsigned short* __restrict__ Wqb,
    unsigned short* __restrict__ Wvb, unsigned short* __restrict__ Wob,
    float* __restrict__ stats) {
  __shared__ float T[64 * 65];
  const int tid = threadIdx.x;
  const int bid = blockIdx.x;
  if (bid < 256) {
    const int b = bid >> 7;
    const int rem = bid & 127;
    const int n0 = (rem >> 2) * 64;
    const int c0 = (rem & 3) * 64;
#pragma unroll
    for (int p = 0; p < 4; ++p) {
      const int idx = tid + 256 * p;
      const int row = idx >> 4, col = (idx & 15) * 4;
      const float4 v =
          *(const float4*)(x + (size_t)(b * CIN_ + c0 + row) * NTOK_ + n0 + col);
      T[row * 65 + col + 0] = v.x; T[row * 65 + col + 1] = v.y;
      T[row * 65 + col + 2] = v.z; T[row * 65 + col + 3] = v.w;
    }
    __syncthreads();
#pragma unroll
    for (int p = 0; p < 2; ++p) {
      const int idx = tid + 256 * p;
      const int nl = idx >> 3, c8 = (idx & 7) * 8;
      unsigned short u[8];
#pragma unroll
      for (int i = 0; i < 8; ++i) u[i] = f2bf(T[(c8 + i) * 65 + nl]);
      *(uint4*)(xT + ((size_t)(b * NTOK_ + n0 + nl)) * CIN_ + c0 + c8) =
          *(uint4*)u;
    }
  } else if (bid < 384) {
    const int t = bid - 256;
    const int which = t >> 5, blk = t & 31;
    const float* src = which == 0 ? WK : which == 1 ? WQ : which == 2 ? WV : Wo;
    unsigned short* dst = which == 0 ? Wkb : which == 1 ? Wqb : which == 2 ? Wvb : Wob;
    const int base = blk * 4096 + tid * 16;
#pragma unroll
    for (int p = 0; p < 4; ++p) {
      const float4 v = *(const float4*)(src + base + p * 4);
      ushort4 u;
      u.x = f2bf(v.x); u.y = f2bf(v.y); u.z = f2bf(v.z); u.w = f2bf(v.w);
      *(ushort4*)(dst + base + p * 4) = u;
    }
  } else {
    for (int i = tid; i < 2 * COUT_; i += 256) stats[i] = 0.f;
  }
}

// ---------------------------------------------------------------------------
// Kernel 1: QKV projection via MFMA. 128f x 128n tile, 4 waves.
// K,Q -> [b][h][n][d] bf16; V (operand-swapped) -> [b][h][d][n] bf16.
// ---------------------------------------------------------------------------
__global__ __launch_bounds__(256) void qkv_kernel(
    const unsigned short* __restrict__ xT, const unsigned short* __restrict__ Wkb,
    const unsigned short* __restrict__ Wqb, const unsigned short* __restrict__ Wvb,
    unsigned short* __restrict__ Kb, unsigned short* __restrict__ Qb,
    unsigned short* __restrict__ Vt) {
  __shared__ unsigned short Wsh[128 * 72];
  __shared__ unsigned short Xsh[128 * 72];
  const int tid = threadIdx.x;
  const int lane = tid & 63, w = tid >> 6;
  const int lx = lane & 15, q = lane >> 4;
  const int wm = w >> 1, wn = w & 1;
  const int n0 = blockIdx.x * 128;
  const int f0 = blockIdx.y * 128;
  const int b = blockIdx.z / 3, which = blockIdx.z % 3;
  const unsigned short* Wb = which == 0 ? Wkb : which == 1 ? Wqb : Wvb;

  const int srow = tid >> 3;
  const int soff = (tid & 7) * 8;
  const unsigned short* Wg = Wb + (size_t)(f0 + srow) * CIN_ + soff;
  const unsigned short* Xg = xT + ((size_t)(b * NTOK_ + n0 + srow)) * CIN_ + soff;

  uint4 wr[4], xr[4];
#pragma unroll
  for (int r = 0; r < 4; ++r) {
    wr[r] = *(const uint4*)(Wg + (size_t)(32 * r) * CIN_);
    xr[r] = *(const uint4*)(Xg + (size_t)(32 * r) * CIN_);
  }

  f32x4 acc[4][4];
#pragma unroll
  for (int i = 0; i < 4; ++i)
#pragma unroll
    for (int j = 0; j < 4; ++j) acc[i][j] = (f32x4){0.f, 0.f, 0.f, 0.f};

  for (int kk = 0; kk < 4; ++kk) {
    __syncthreads();
#pragma unroll
    for (int r = 0; r < 4; ++r) {
      *(uint4*)(Wsh + (srow + 32 * r) * 72 + soff) = wr[r];
      *(uint4*)(Xsh + (srow + 32 * r) * 72 + soff) = xr[r];
    }
    if (kk < 3) {
      const int c0 = (kk + 1) * 64;
#pragma unroll
      for (int r = 0; r < 4; ++r) {
        wr[r] = *(const uint4*)(Wg + (size_t)(32 * r) * CIN_ + c0);
        xr[r] = *(const uint4*)(Xg + (size_t)(32 * r) * CIN_ + c0);
      }
    }
    __syncthreads();
    short8 xF[4][2];
#pragma unroll
    for (int i = 0; i < 4; ++i) {
      xF[i][0] = *(const short8*)(Xsh + (64 * wn + 16 * i + lx) * 72 + q * 8);
      xF[i][1] = *(const short8*)(Xsh + (64 * wn + 16 * i + lx) * 72 + 32 + q * 8);
    }
    if (which < 2) {
#pragma unroll
      for (int i = 0; i < 4; ++i) {
        const short8 w0 = *(const short8*)(Wsh + (64 * wm + 16 * i + lx) * 72 + q * 8);
        const short8 w1 = *(const short8*)(Wsh + (64 * wm + 16 * i + lx) * 72 + 32 + q * 8);
#pragma unroll
        for (int j = 0; j < 4; ++j) {
          acc[i][j] = __builtin_amdgcn_mfma_f32_16x16x32_bf16(w0, xF[j][0], acc[i][j], 0, 0, 0);
          acc[i][j] = __builtin_amdgcn_mfma_f32_16x16x32_bf16(w1, xF[j][1], acc[i][j], 0, 0, 0);
        }
      }
    } else {
#pragma unroll
      for (int j = 0; j < 4; ++j) {
        const short8 w0 = *(const short8*)(Wsh + (64 * wm + 16 * j + lx) * 72 + q * 8);
        const short8 w1 = *(const short8*)(Wsh + (64 * wm + 16 * j + lx) * 72 + 32 + q * 8);
#pragma unroll
        for (int i = 0; i < 4; ++i) {
          acc[i][j] = __builtin_amdgcn_mfma_f32_16x16x32_bf16(xF[i][0], w0, acc[i][j], 0, 0, 0);
          acc[i][j] = __builtin_amdgcn_mfma_f32_16x16x32_bf16(xF[i][1], w1, acc[i][j], 0, 0, 0);
        }
      }
    }
  }

  const int h = (f0 >> 6) + wm;
  if (which < 2) {
    unsigned short* Y = (which == 0 ? Kb : Qb);
#pragma unroll
    for (int i = 0; i < 4; ++i)
#pragma unroll
      for (int j = 0; j < 4; ++j) {
        const int n = n0 + 64 * wn + 16 * j + lx;
        const int d0 = 16 * i + 4 * q;
        ushort4 u;
        u.x = f2bf(acc[i][j][0]); u.y = f2bf(acc[i][j][1]);
        u.z = f2bf(acc[i][j][2]); u.w = f2bf(acc[i][j][3]);
        *(ushort4*)(Y + ((size_t)((b * NH_ + h) * NTOK_ + n)) * DH_ + d0) = u;
      }
  } else {
#pragma unroll
    for (int i = 0; i < 4; ++i)
#pragma unroll
      for (int j = 0; j < 4; ++j) {
        const int d = 16 * j + lx;
        const int n = n0 + 64 * wn + 16 * i + 4 * q;
        ushort4 u;
        u.x = f2bf(acc[i][j][0]); u.y = f2bf(acc[i][j][1]);
        u.z = f2bf(acc[i][j][2]); u.w = f2bf(acc[i][j][3]);
        *(ushort4*)(Vt + ((size_t)((b * NH_ + h) * DH_ + d)) * NTOK_ + n) = u;
      }
  }
}

// ---------------------------------------------------------------------------
// Kernel 2: block-causal attention — BARRIER-FREE j-loop.
// 512 blocks = 32 i-tiles x 16 bh; bid = iblk*16 + bh so XCD (bid&7) <-> bh&7
// (each XCD's L2 holds only 2 heads' Q/V ~1 MB).
// All MFMA operands loaded per-lane straight from global (K rows 16w+lx,
// Q rows j0+16s+lx, V^T rows 16s+lx) — no LDS staging, no __syncthreads in
// the loop. Only P's C->A layout transform uses LDS, wave-private (lgkmcnt).
// Unshifted exp2 softmax (scores bounded); row sums reduced once at the end.
// ---------------------------------------------------------------------------
__global__ __launch_bounds__(256) void attn_kernel(
    const unsigned short* __restrict__ Kb, const unsigned short* __restrict__ Qb,
    const unsigned short* __restrict__ Vt, unsigned short* __restrict__ Ob) {
  __shared__ __align__(16) unsigned short Psh[4 * 16 * 72];  // per-wave 16x72

  const int tid = threadIdx.x;
  const int lane = tid & 63;
  const int w = tid >> 6;
  const int lx = lane & 15;
  const int q = lane >> 4;

  const int bid = blockIdx.x;      // 0..511
  const int iblk = bid >> 4;
  const int bh = bid & 15;
  const int h = bh & 7, b = bh >> 3;
  const int i0 = iblk * 64;
  const int njt = ((iblk >> 1) + 1) * 2;

  const size_t bhs = (size_t)b * NH_ + h;
  const unsigned short* Kg = Kb + bhs * (size_t)NTOK_ * DH_ + (size_t)i0 * DH_;
  const unsigned short* Qg = Qb + bhs * (size_t)NTOK_ * DH_;
  const unsigned short* Vg = Vt + bhs * (size_t)DH_ * NTOK_;

  // K A-frags straight from global: m=lx -> token row i0+16w+lx
  const short8 aK0 = *(const short8*)(Kg + (16 * w + lx) * DH_ + q * 8);
  const short8 aK1 = *(const short8*)(Kg + (16 * w + lx) * DH_ + 32 + q * 8);

  unsigned short* Pw = Psh + w * 16 * 72;

  f32x4 o[4];      // O^T accum: row d=16s+4q+r, col i=lx (token i0+16w+lx)
#pragma unroll
  for (int s = 0; s < 4; ++s) o[s] = (f32x4){0.f, 0.f, 0.f, 0.f};
  float rsum[4] = {0.f, 0.f, 0.f, 0.f};

  for (int jt = 0; jt < njt; ++jt) {
    const int j0 = jt * 64;
    // issue all 16 dwordx4 loads up front (MLP; no barriers anywhere)
    short8 bq[4][2], va[4][2];
#pragma unroll
    for (int s = 0; s < 4; ++s) {
      const unsigned short* qrow = Qg + (size_t)(j0 + 16 * s + lx) * DH_;
      const unsigned short* vrow = Vg + (size_t)(16 * s + lx) * NTOK_ + j0;
      bq[s][0] = *(const short8*)(qrow + q * 8);
      bq[s][1] = *(const short8*)(qrow + 32 + q * 8);
      va[s][0] = *(const short8*)(vrow + q * 8);
      va[s][1] = *(const short8*)(vrow + 32 + q * 8);
    }

    // S-phase: S[16i x 64j] (row i=4q+r local, col j=16s+lx)
    f32x4 sa[4];
#pragma unroll
    for (int s = 0; s < 4; ++s) {
      sa[s] = (f32x4){0.f, 0.f, 0.f, 0.f};
      sa[s] = __builtin_amdgcn_mfma_f32_16x16x32_bf16(aK0, bq[s][0], sa[s], 0, 0, 0);
      sa[s] = __builtin_amdgcn_mfma_f32_16x16x32_bf16(aK1, bq[s][1], sa[s], 0, 0, 0);
    }

    // unshifted exponentials; per-lane row-sum partials; P -> wave-private LDS
#pragma unroll
    for (int s = 0; s < 4; ++s)
#pragma unroll
      for (int r = 0; r < 4; ++r) {
        const float p = __builtin_amdgcn_exp2f(sa[s][r] * SCALE_LOG2_);
        rsum[r] += p;
        Pw[(q * 4 + r) * 72 + 16 * s + lx] = f2bf(p);
      }
    asm volatile("s_waitcnt lgkmcnt(0)" ::: "memory");  // own-wave P visible

    // PV^T: O^T[64d x 16i] += V^T[64d x 64j] * P^T[64j x 16i]
    const short8 pb0 = *(const short8*)(Pw + lx * 72 + q * 8);
    const short8 pb1 = *(const short8*)(Pw + lx * 72 + 32 + q * 8);
#pragma unroll
    for (int s = 0; s < 4; ++s) {
      o[s] = __builtin_amdgcn_mfma_f32_16x16x32_bf16(va[s][0], pb0, o[s], 0, 0, 0);
      o[s] = __builtin_amdgcn_mfma_f32_16x16x32_bf16(va[s][1], pb1, o[s], 0, 0, 0);
    }
  }

  // reduce row sums across the 16 lanes of each q-group (once per block)
#pragma unroll
  for (int r = 0; r < 4; ++r) {
#pragma unroll
    for (int off = 1; off < 16; off <<= 1) rsum[r] += __shfl_xor(rsum[r], off);
  }
  // per-lane 1/l for own column (row i local = lx, held by lane (lx>>2)*16, comp lx&3)
  const int gsrc = ((lx >> 2) << 4);
  const float u0 = __shfl(rsum[0], gsrc);
  const float u1 = __shfl(rsum[1], gsrc);
  const float u2 = __shfl(rsum[2], gsrc);
  const float u3 = __shfl(rsum[3], gsrc);
  const float lsel = (lx & 2) ? ((lx & 1) ? u3 : u2) : ((lx & 1) ? u1 : u0);
  const float invl = 1.0f / lsel;
  const int n = i0 + 16 * w + lx;
#pragma unroll
  for (int s = 0; s < 4; ++s) {
    ushort4 u;
    u.x = f2bf(o[s][0] * invl); u.y = f2bf(o[s][1] * invl);
    u.z = f2bf(o[s][2] * invl); u.w = f2bf(o[s][3] * invl);
    *(ushort4*)(Ob + ((size_t)(b * NTOK_ + n)) * FF_ + h * 64 + 16 * s + 4 * q) = u;
  }
}

// ---------------------------------------------------------------------------
// Kernel 3: output projection via MFMA + bias + ReLU + skip -> d_out fp32,
// + BN stats (shuffle-reduced atomics).
// ---------------------------------------------------------------------------
__global__ __launch_bounds__(256) void proj_kernel(
    const unsigned short* __restrict__ Ob, const unsigned short* __restrict__ Wob,
    const float* __restrict__ bo, const float* __restrict__ x,
    float* __restrict__ pre, float* __restrict__ stats) {
  __shared__ unsigned short Osh[64 * 72];
  __shared__ unsigned short Wsh[64 * 72];
  const int tid = threadIdx.x;
  const int lane = tid & 63, w = tid >> 6;
  const int lx = lane & 15, q = lane >> 4;
  const int wn = w & 1, wo = w >> 1;
  const int n0 = blockIdx.x * 64;
  const int o0 = blockIdx.y * 64;
  const int b = blockIdx.z;

  const int srow = tid >> 3;
  const int soff = (tid & 7) * 8;
  const unsigned short* Og = Ob + ((size_t)(b * NTOK_ + n0 + srow)) * FF_ + soff;
  const unsigned short* Wg = Wob + (size_t)(o0 + srow) * FF_ + soff;

  uint4 orr[2], wrr[2];
#pragma unroll
  for (int r = 0; r < 2; ++r) {
    orr[r] = *(const uint4*)(Og + (size_t)(32 * r) * FF_);
    wrr[r] = *(const uint4*)(Wg + (size_t)(32 * r) * FF_);
  }

  f32x4 acc[2][2];
#pragma unroll
  for (int i = 0; i < 2; ++i)
#pragma unroll
    for (int j = 0; j < 2; ++j) acc[i][j] = (f32x4){0.f, 0.f, 0.f, 0.f};

  for (int kk = 0; kk < 8; ++kk) {
    __syncthreads();
#pragma unroll
    for (int r = 0; r < 2; ++r) {
      *(uint4*)(Osh + (srow + 32 * r) * 72 + soff) = orr[r];
      *(uint4*)(Wsh + (srow + 32 * r) * 72 + soff) = wrr[r];
    }
    if (kk < 7) {
      const int c0 = (kk + 1) * 64;
#pragma unroll
      for (int r = 0; r < 2; ++r) {
        orr[r] = *(const uint4*)(Og + (size_t)(32 * r) * FF_ + c0);
        wrr[r] = *(const uint4*)(Wg + (size_t)(32 * r) * FF_ + c0);
      }
    }
    __syncthreads();
    short8 aF[2][2], bF[2][2];
#pragma unroll
    for (int i = 0; i < 2; ++i) {
      aF[i][0] = *(const short8*)(Osh + (32 * wn + 16 * i + lx) * 72 + q * 8);
      aF[i][1] = *(const short8*)(Osh + (32 * wn + 16 * i + lx) * 72 + 32 + q * 8);
      bF[i][0] = *(const short8*)(Wsh + (32 * wo + 16 * i + lx) * 72 + q * 8);
      bF[i][1] = *(const short8*)(Wsh + (32 * wo + 16 * i + lx) * 72 + 32 + q * 8);
    }
#pragma unroll
    for (int i = 0; i < 2; ++i)
#pragma unroll
      for (int j = 0; j < 2; ++j) {
        acc[i][j] = __builtin_amdgcn_mfma_f32_16x16x32_bf16(aF[i][0], bF[j][0], acc[i][j], 0, 0, 0);
        acc[i][j] = __builtin_amdgcn_mfma_f32_16x16x32_bf16(aF[i][1], bF[j][1], acc[i][j], 0, 0, 0);
      }
  }

  float s[2] = {0.f, 0.f}, s2[2] = {0.f, 0.f};
#pragma unroll
  for (int j = 0; j < 2; ++j) {
    const int o = o0 + 32 * wo + 16 * j + lx;
    const float bias = bo[o];
#pragma unroll
    for (int i = 0; i < 2; ++i) {
      const int n = n0 + 32 * wn + 16 * i + 4 * q;
      const float4 xv = *(const float4*)(x + ((size_t)(b * CIN_ + o)) * NTOK_ + n);
      float4 v;
      v.x = fmaxf(acc[i][j][0] + bias, 0.f) + xv.x;
      v.y = fmaxf(acc[i][j][1] + bias, 0.f) + xv.y;
      v.z = fmaxf(acc[i][j][2] + bias, 0.f) + xv.z;
      v.w = fmaxf(acc[i][j][3] + bias, 0.f) + xv.w;
      *(float4*)(pre + ((size_t)(b * COUT_ + o)) * NTOK_ + n) = v;
      s[j] += v.x + v.y + v.z + v.w;
      s2[j] += v.x * v.x + v.y * v.y + v.z * v.z + v.w * v.w;
    }
  }
#pragma unroll
  for (int j = 0; j < 2; ++j) {
    s[j] += __shfl_xor(s[j], 16);  s[j] += __shfl_xor(s[j], 32);
    s2[j] += __shfl_xor(s2[j], 16); s2[j] += __shfl_xor(s2[j], 32);
  }
  if (lane < 16) {
#pragma unroll
    for (int j = 0; j < 2; ++j) {
      const int o = o0 + 32 * wo + 16 * j + lx;
      atomicAdd(&stats[o], s[j]);
      atomicAdd(&stats[COUT_ + o], s2[j]);
    }
  }
}

// ---------------------------------------------------------------------------
// Kernel 4: BatchNorm finalize, in place on d_out.
// ---------------------------------------------------------------------------
__global__ __launch_bounds__(256) void bn_kernel(
    float* __restrict__ out, const float* __restrict__ stats,
    const float* __restrict__ gamma, const float* __restrict__ beta) {
  const int idx = blockIdx.x * 256 + threadIdx.x;
  const int e = idx * 4;
  const int c = (e >> 11) & (COUT_ - 1);
  const float inv = 1.0f / (float)(BB_ * NTOK_);
  const float mean = stats[c] * inv;
  const float var = stats[COUT_ + c] * inv - mean * mean;
  const float sc = rsqrtf(var + BNEPS_) * gamma[c];
  const float bt = beta[c];
  float4 v = *(float4*)(out + e);
  v.x = (v.x - mean) * sc + bt;
  v.y = (v.y - mean) * sc + bt;
  v.z = (v.z - mean) * sc + bt;
  v.w = (v.w - mean) * sc + bt;
  *(float4*)(out + e) = v;
}

extern "C" void kernel_launch(void* const* d_in, const int* in_sizes, int n_in,
                              void* d_out, int out_size, void* d_ws, size_t ws_size,
                              hipStream_t stream) {
  (void)in_sizes; (void)n_in; (void)out_size; (void)ws_size;
  const float* x = (const float*)d_in[0];
  const float* WK = (const float*)d_in[1];
  const float* WQ = (const float*)d_in[2];
  const float* WV = (const float*)d_in[3];
  const float* Wo = (const float*)d_in[4];
  const float* bo = (const float*)d_in[5];
  const float* gamma = (const float*)d_in[6];
  const float* beta = (const float*)d_in[7];

  char* ws = (char*)d_ws;
  unsigned short* xT  = (unsigned short*)(ws);                    // 2 MB
  unsigned short* Wkb = (unsigned short*)(ws + 2097152);          // 256 KB x4
  unsigned short* Wqb = (unsigned short*)(ws + 2359296);
  unsigned short* Wvb = (unsigned short*)(ws + 2621440);
  unsigned short* Wob = (unsigned short*)(ws + 2883584);
  unsigned short* Kb  = (unsigned short*)(ws + 3145728);          // 4 MB
  unsigned short* Qb  = (unsigned short*)(ws + 7340032);          // 4 MB
  unsigned short* Vt  = (unsigned short*)(ws + 11534336);         // 4 MB
  unsigned short* Ob  = (unsigned short*)(ws + 15728640);         // 4 MB
  float* stats        = (float*)(ws + 19922944);                  // 2 KB
  float* out = (float*)d_out;

  prep_kernel<<<385, 256, 0, stream>>>(x, WK, WQ, WV, Wo, xT, Wkb, Wqb, Wvb, Wob, stats);
  qkv_kernel<<<dim3(16, 4, 6), 256, 0, stream>>>(xT, Wkb, Wqb, Wvb, Kb, Qb, Vt);
  attn_kernel<<<dim3(512, 1, 1), 256, 0, stream>>>(Kb, Qb, Vt, Ob);
  proj_kernel<<<dim3(32, 4, 2), 256, 0, stream>>>(Ob, Wob, bo, x, out, stats);
  bn_kernel<<<1024, 256, 0, stream>>>(out, stats, gamma, beta);
}

// Round 6
// 179.506 us; speedup vs baseline: 1.1333x; 1.1333x over previous
//
#include <hip/hip_runtime.h>
#include <math.h>

#define BB_   2
#define CIN_  256
#define NTOK_ 2048
#define FF_   512
#define COUT_ 256
#define NH_   8
#define DH_   64
#define HW_   128
#define BNEPS_ 1e-5f
#define SCALE_LOG2_ 0.09016844005556021f  /* log2(e)/16 */

typedef __attribute__((ext_vector_type(8))) short short8;
typedef __attribute__((ext_vector_type(4))) float f32x4;

__device__ inline unsigned short f2bf(float f) {
  union { float f; unsigned u; } v; v.f = f;
  unsigned r = (v.u + 0x7FFF + ((v.u >> 16) & 1)) >> 16;  // RNE
  return (unsigned short)r;
}
__device__ inline float bf2f(unsigned short u) {
  union { unsigned u; float f; } v; v.u = ((unsigned)u) << 16;
  return v.f;
}

// ---------------------------------------------------------------------------
// Kernel 0: prep — x fp32 [b][c][n] -> xT bf16 [b][n][c] (LDS transpose);
// weights fp32 -> bf16 flat; zero BN stats.
// ---------------------------------------------------------------------------
__global__ __launch_bounds__(256) void prep_kernel(
    const float* __restrict__ x, const float* __restrict__ WK,
    const float* __restrict__ WQ, const float* __restrict__ WV,
    const float* __restrict__ Wo, unsigned short* __restrict__ xT,
    unsigned short* __restrict__ Wkb, unsigned short* __restrict__ Wqb,
    unsigned short* __restrict__ Wvb, unsigned short* __restrict__ Wob,
    float* __restrict__ stats) {
  __shared__ float T[64 * 65];
  const int tid = threadIdx.x;
  const int bid = blockIdx.x;
  if (bid < 256) {
    const int b = bid >> 7;
    const int rem = bid & 127;
    const int n0 = (rem >> 2) * 64;
    const int c0 = (rem & 3) * 64;
#pragma unroll
    for (int p = 0; p < 4; ++p) {
      const int idx = tid + 256 * p;
      const int row = idx >> 4, col = (idx & 15) * 4;
      const float4 v =
          *(const float4*)(x + (size_t)(b * CIN_ + c0 + row) * NTOK_ + n0 + col);
      T[row * 65 + col + 0] = v.x; T[row * 65 + col + 1] = v.y;
      T[row * 65 + col + 2] = v.z; T[row * 65 + col + 3] = v.w;
    }
    __syncthreads();
#pragma unroll
    for (int p = 0; p < 2; ++p) {
      const int idx = tid + 256 * p;
      const int nl = idx >> 3, c8 = (idx & 7) * 8;
      unsigned short u[8];
#pragma unroll
      for (int i = 0; i < 8; ++i) u[i] = f2bf(T[(c8 + i) * 65 + nl]);
      *(uint4*)(xT + ((size_t)(b * NTOK_ + n0 + nl)) * CIN_ + c0 + c8) =
          *(uint4*)u;
    }
  } else if (bid < 384) {
    const int t = bid - 256;
    const int which = t >> 5, blk = t & 31;
    const float* src = which == 0 ? WK : which == 1 ? WQ : which == 2 ? WV : Wo;
    unsigned short* dst = which == 0 ? Wkb : which == 1 ? Wqb : which == 2 ? Wvb : Wob;
    const int base = blk * 4096 + tid * 16;
#pragma unroll
    for (int p = 0; p < 4; ++p) {
      const float4 v = *(const float4*)(src + base + p * 4);
      ushort4 u;
      u.x = f2bf(v.x); u.y = f2bf(v.y); u.z = f2bf(v.z); u.w = f2bf(v.w);
      *(ushort4*)(dst + base + p * 4) = u;
    }
  } else {
    for (int i = tid; i < 2 * COUT_; i += 256) stats[i] = 0.f;
  }
}

// ---------------------------------------------------------------------------
// Kernel 1: QKV projection via MFMA. 128f x 128n tile, 4 waves.
// (256,2): min 2 waves/EU -> 256-VGPR cap so staging+acc+frags stay resident.
// K,Q -> [b][h][n][d] bf16; V (operand-swapped) -> [b][h][d][n] bf16.
// ---------------------------------------------------------------------------
__global__ __launch_bounds__(256, 2) void qkv_kernel(
    const unsigned short* __restrict__ xT, const unsigned short* __restrict__ Wkb,
    const unsigned short* __restrict__ Wqb, const unsigned short* __restrict__ Wvb,
    unsigned short* __restrict__ Kb, unsigned short* __restrict__ Qb,
    unsigned short* __restrict__ Vt) {
  __shared__ unsigned short Wsh[128 * 72];
  __shared__ unsigned short Xsh[128 * 72];
  const int tid = threadIdx.x;
  const int lane = tid & 63, w = tid >> 6;
  const int lx = lane & 15, q = lane >> 4;
  const int wm = w >> 1, wn = w & 1;
  const int n0 = blockIdx.x * 128;
  const int f0 = blockIdx.y * 128;
  const int b = blockIdx.z / 3, which = blockIdx.z % 3;
  const unsigned short* Wb = which == 0 ? Wkb : which == 1 ? Wqb : Wvb;

  const int srow = tid >> 3;
  const int soff = (tid & 7) * 8;
  const unsigned short* Wg = Wb + (size_t)(f0 + srow) * CIN_ + soff;
  const unsigned short* Xg = xT + ((size_t)(b * NTOK_ + n0 + srow)) * CIN_ + soff;

  uint4 wr[4], xr[4];
#pragma unroll
  for (int r = 0; r < 4; ++r) {
    wr[r] = *(const uint4*)(Wg + (size_t)(32 * r) * CIN_);
    xr[r] = *(const uint4*)(Xg + (size_t)(32 * r) * CIN_);
  }

  f32x4 acc[4][4];
#pragma unroll
  for (int i = 0; i < 4; ++i)
#pragma unroll
    for (int j = 0; j < 4; ++j) acc[i][j] = (f32x4){0.f, 0.f, 0.f, 0.f};

  for (int kk = 0; kk < 4; ++kk) {
    __syncthreads();
#pragma unroll
    for (int r = 0; r < 4; ++r) {
      *(uint4*)(Wsh + (srow + 32 * r) * 72 + soff) = wr[r];
      *(uint4*)(Xsh + (srow + 32 * r) * 72 + soff) = xr[r];
    }
    if (kk < 3) {
      const int c0 = (kk + 1) * 64;
#pragma unroll
      for (int r = 0; r < 4; ++r) {
        wr[r] = *(const uint4*)(Wg + (size_t)(32 * r) * CIN_ + c0);
        xr[r] = *(const uint4*)(Xg + (size_t)(32 * r) * CIN_ + c0);
      }
    }
    __syncthreads();
    short8 xF[4][2];
#pragma unroll
    for (int i = 0; i < 4; ++i) {
      xF[i][0] = *(const short8*)(Xsh + (64 * wn + 16 * i + lx) * 72 + q * 8);
      xF[i][1] = *(const short8*)(Xsh + (64 * wn + 16 * i + lx) * 72 + 32 + q * 8);
    }
    if (which < 2) {
#pragma unroll
      for (int i = 0; i < 4; ++i) {
        const short8 w0 = *(const short8*)(Wsh + (64 * wm + 16 * i + lx) * 72 + q * 8);
        const short8 w1 = *(const short8*)(Wsh + (64 * wm + 16 * i + lx) * 72 + 32 + q * 8);
#pragma unroll
        for (int j = 0; j < 4; ++j) {
          acc[i][j] = __builtin_amdgcn_mfma_f32_16x16x32_bf16(w0, xF[j][0], acc[i][j], 0, 0, 0);
          acc[i][j] = __builtin_amdgcn_mfma_f32_16x16x32_bf16(w1, xF[j][1], acc[i][j], 0, 0, 0);
        }
      }
    } else {
#pragma unroll
      for (int j = 0; j < 4; ++j) {
        const short8 w0 = *(const short8*)(Wsh + (64 * wm + 16 * j + lx) * 72 + q * 8);
        const short8 w1 = *(const short8*)(Wsh + (64 * wm + 16 * j + lx) * 72 + 32 + q * 8);
#pragma unroll
        for (int i = 0; i < 4; ++i) {
          acc[i][j] = __builtin_amdgcn_mfma_f32_16x16x32_bf16(xF[i][0], w0, acc[i][j], 0, 0, 0);
          acc[i][j] = __builtin_amdgcn_mfma_f32_16x16x32_bf16(xF[i][1], w1, acc[i][j], 0, 0, 0);
        }
      }
    }
  }

  const int h = (f0 >> 6) + wm;
  if (which < 2) {
    unsigned short* Y = (which == 0 ? Kb : Qb);
#pragma unroll
    for (int i = 0; i < 4; ++i)
#pragma unroll
      for (int j = 0; j < 4; ++j) {
        const int n = n0 + 64 * wn + 16 * j + lx;
        const int d0 = 16 * i + 4 * q;
        ushort4 u;
        u.x = f2bf(acc[i][j][0]); u.y = f2bf(acc[i][j][1]);
        u.z = f2bf(acc[i][j][2]); u.w = f2bf(acc[i][j][3]);
        *(ushort4*)(Y + ((size_t)((b * NH_ + h) * NTOK_ + n)) * DH_ + d0) = u;
      }
  } else {
#pragma unroll
    for (int i = 0; i < 4; ++i)
#pragma unroll
      for (int j = 0; j < 4; ++j) {
        const int d = 16 * j + lx;
        const int n = n0 + 64 * wn + 16 * i + 4 * q;
        ushort4 u;
        u.x = f2bf(acc[i][j][0]); u.y = f2bf(acc[i][j][1]);
        u.z = f2bf(acc[i][j][2]); u.w = f2bf(acc[i][j][3]);
        *(ushort4*)(Vt + ((size_t)((b * NH_ + h) * DH_ + d)) * NTOK_ + n) = u;
      }
  }
}

// ---------------------------------------------------------------------------
// Kernel 2: block-causal attention — barrier-free j-loop, REGISTER-PIPELINED.
// __launch_bounds__(256,2): 256-VGPR cap so two full tile-buffers (A/B, 128
// VGPRs) + accumulators + K-frags stay resident; 16 loads/tile issue in bulk
// and stay in flight across the paired-iteration pipeline (njt always even).
// LPT pairing: bids 0..255 heavy (iblk 31..16), 256..511 light (0..15) so
// co-resident pairs sum to ~34 iters; bh = bid&15 keeps XCD<->head locality.
// Wave-private P transpose in LDS (lgkmcnt only, no __syncthreads anywhere).
// ---------------------------------------------------------------------------
__global__ __launch_bounds__(256, 2) void attn_kernel(
    const unsigned short* __restrict__ Kb, const unsigned short* __restrict__ Qb,
    const unsigned short* __restrict__ Vt, unsigned short* __restrict__ Ob) {
  __shared__ __align__(16) unsigned short Psh[4 * 16 * 72];  // per-wave 16x72

  const int tid = threadIdx.x;
  const int lane = tid & 63;
  const int w = tid >> 6;
  const int lx = lane & 15;
  const int q = lane >> 4;

  const int bid = blockIdx.x;      // 0..511
  const int u = bid >> 4;
  const int iblk = (u < 16) ? (31 - u) : (u - 16);
  const int bh = bid & 15;
  const int h = bh & 7, b = bh >> 3;
  const int i0 = iblk * 64;
  const int njt = ((iblk >> 1) + 1) * 2;   // always even, >= 2

  const size_t bhs = (size_t)b * NH_ + h;
  const unsigned short* Kg = Kb + bhs * (size_t)NTOK_ * DH_ + (size_t)i0 * DH_;
  const unsigned short* Qg = Qb + bhs * (size_t)NTOK_ * DH_;
  const unsigned short* Vg = Vt + bhs * (size_t)DH_ * NTOK_;

  // K A-frags straight from global: m=lx -> token row i0+16w+lx
  const short8 aK0 = *(const short8*)(Kg + (16 * w + lx) * DH_ + q * 8);
  const short8 aK1 = *(const short8*)(Kg + (16 * w + lx) * DH_ + 32 + q * 8);

  unsigned short* Pw = Psh + w * 16 * 72;

  f32x4 o[4];      // O^T accum: row d=16s+4q+r, col i=lx (token i0+16w+lx)
#pragma unroll
  for (int s = 0; s < 4; ++s) o[s] = (f32x4){0.f, 0.f, 0.f, 0.f};
  float rsum[4] = {0.f, 0.f, 0.f, 0.f};

  struct Frag { short8 q0[4], q1[4], v0[4], v1[4]; };

  auto loadTile = [&](Frag& F, int j0) {
#pragma unroll
    for (int s = 0; s < 4; ++s) {
      const unsigned short* qrow = Qg + (size_t)(j0 + 16 * s + lx) * DH_;
      const unsigned short* vrow = Vg + (size_t)(16 * s + lx) * NTOK_ + j0;
      F.q0[s] = *(const short8*)(qrow + q * 8);
      F.q1[s] = *(const short8*)(qrow + 32 + q * 8);
      F.v0[s] = *(const short8*)(vrow + q * 8);
      F.v1[s] = *(const short8*)(vrow + 32 + q * 8);
    }
  };

  auto compute = [&](const Frag& F) {
    // S-phase: S[16i x 64j] (row i=4q+r local, col j=16s+lx)
    f32x4 sa[4];
#pragma unroll
    for (int s = 0; s < 4; ++s) {
      sa[s] = (f32x4){0.f, 0.f, 0.f, 0.f};
      sa[s] = __builtin_amdgcn_mfma_f32_16x16x32_bf16(aK0, F.q0[s], sa[s], 0, 0, 0);
      sa[s] = __builtin_amdgcn_mfma_f32_16x16x32_bf16(aK1, F.q1[s], sa[s], 0, 0, 0);
    }
    // unshifted exponentials; per-lane row-sum partials; P -> wave-private LDS
#pragma unroll
    for (int s = 0; s < 4; ++s)
#pragma unroll
      for (int r = 0; r < 4; ++r) {
        const float p = __builtin_amdgcn_exp2f(sa[s][r] * SCALE_LOG2_);
        rsum[r] += p;
        Pw[(q * 4 + r) * 72 + 16 * s + lx] = f2bf(p);
      }
    asm volatile("s_waitcnt lgkmcnt(0)" ::: "memory");  // own-wave P visible
    // PV^T: O^T[64d x 16i] += V^T[64d x 64j] * P^T[64j x 16i]
    const short8 pb0 = *(const short8*)(Pw + lx * 72 + q * 8);
    const short8 pb1 = *(const short8*)(Pw + lx * 72 + 32 + q * 8);
#pragma unroll
    for (int s = 0; s < 4; ++s) {
      o[s] = __builtin_amdgcn_mfma_f32_16x16x32_bf16(F.v0[s], pb0, o[s], 0, 0, 0);
      o[s] = __builtin_amdgcn_mfma_f32_16x16x32_bf16(F.v1[s], pb1, o[s], 0, 0, 0);
    }
  };

  Frag A, B;
  loadTile(A, 0);
  for (int jt = 0; jt < njt; jt += 2) {
    loadTile(B, (jt + 1) * 64);      // in flight while A computes
    compute(A);
    if (jt + 2 < njt) loadTile(A, (jt + 2) * 64);  // in flight while B computes
    compute(B);
  }

  // reduce row sums across the 16 lanes of each q-group (once per block)
#pragma unroll
  for (int r = 0; r < 4; ++r) {
#pragma unroll
    for (int off = 1; off < 16; off <<= 1) rsum[r] += __shfl_xor(rsum[r], off);
  }
  // per-lane 1/l for own column (row i local = lx, held by lane (lx>>2)*16, comp lx&3)
  const int gsrc = ((lx >> 2) << 4);
  const float u0 = __shfl(rsum[0], gsrc);
  const float u1 = __shfl(rsum[1], gsrc);
  const float u2 = __shfl(rsum[2], gsrc);
  const float u3 = __shfl(rsum[3], gsrc);
  const float lsel = (lx & 2) ? ((lx & 1) ? u3 : u2) : ((lx & 1) ? u1 : u0);
  const float invl = 1.0f / lsel;
  const int n = i0 + 16 * w + lx;
#pragma unroll
  for (int s = 0; s < 4; ++s) {
    ushort4 uo;
    uo.x = f2bf(o[s][0] * invl); uo.y = f2bf(o[s][1] * invl);
    uo.z = f2bf(o[s][2] * invl); uo.w = f2bf(o[s][3] * invl);
    *(ushort4*)(Ob + ((size_t)(b * NTOK_ + n)) * FF_ + h * 64 + 16 * s + 4 * q) = uo;
  }
}

// ---------------------------------------------------------------------------
// Kernel 3: output projection via MFMA + bias + ReLU + skip -> d_out fp32,
// + BN stats (shuffle-reduced atomics).
// ---------------------------------------------------------------------------
__global__ __launch_bounds__(256) void proj_kernel(
    const unsigned short* __restrict__ Ob, const unsigned short* __restrict__ Wob,
    const float* __restrict__ bo, const float* __restrict__ x,
    float* __restrict__ pre, float* __restrict__ stats) {
  __shared__ unsigned short Osh[64 * 72];
  __shared__ unsigned short Wsh[64 * 72];
  const int tid = threadIdx.x;
  const int lane = tid & 63, w = tid >> 6;
  const int lx = lane & 15, q = lane >> 4;
  const int wn = w & 1, wo = w >> 1;
  const int n0 = blockIdx.x * 64;
  const int o0 = blockIdx.y * 64;
  const int b = blockIdx.z;

  const int srow = tid >> 3;
  const int soff = (tid & 7) * 8;
  const unsigned short* Og = Ob + ((size_t)(b * NTOK_ + n0 + srow)) * FF_ + soff;
  const unsigned short* Wg = Wob + (size_t)(o0 + srow) * FF_ + soff;

  uint4 orr[2], wrr[2];
#pragma unroll
  for (int r = 0; r < 2; ++r) {
    orr[r] = *(const uint4*)(Og + (size_t)(32 * r) * FF_);
    wrr[r] = *(const uint4*)(Wg + (size_t)(32 * r) * FF_);
  }

  f32x4 acc[2][2];
#pragma unroll
  for (int i = 0; i < 2; ++i)
#pragma unroll
    for (int j = 0; j < 2; ++j) acc[i][j] = (f32x4){0.f, 0.f, 0.f, 0.f};

  for (int kk = 0; kk < 8; ++kk) {
    __syncthreads();
#pragma unroll
    for (int r = 0; r < 2; ++r) {
      *(uint4*)(Osh + (srow + 32 * r) * 72 + soff) = orr[r];
      *(uint4*)(Wsh + (srow + 32 * r) * 72 + soff) = wrr[r];
    }
    if (kk < 7) {
      const int c0 = (kk + 1) * 64;
#pragma unroll
      for (int r = 0; r < 2; ++r) {
        orr[r] = *(const uint4*)(Og + (size_t)(32 * r) * FF_ + c0);
        wrr[r] = *(const uint4*)(Wg + (size_t)(32 * r) * FF_ + c0);
      }
    }
    __syncthreads();
    short8 aF[2][2], bF[2][2];
#pragma unroll
    for (int i = 0; i < 2; ++i) {
      aF[i][0] = *(const short8*)(Osh + (32 * wn + 16 * i + lx) * 72 + q * 8);
      aF[i][1] = *(const short8*)(Osh + (32 * wn + 16 * i + lx) * 72 + 32 + q * 8);
      bF[i][0] = *(const short8*)(Wsh + (32 * wo + 16 * i + lx) * 72 + q * 8);
      bF[i][1] = *(const short8*)(Wsh + (32 * wo + 16 * i + lx) * 72 + 32 + q * 8);
    }
#pragma unroll
    for (int i = 0; i < 2; ++i)
#pragma unroll
      for (int j = 0; j < 2; ++j) {
        acc[i][j] = __builtin_amdgcn_mfma_f32_16x16x32_bf16(aF[i][0], bF[j][0], acc[i][j], 0, 0, 0);
        acc[i][j] = __builtin_amdgcn_mfma_f32_16x16x32_bf16(aF[i][1], bF[j][1], acc[i][j], 0, 0, 0);
      }
  }

  float s[2] = {0.f, 0.f}, s2[2] = {0.f, 0.f};
#pragma unroll
  for (int j = 0; j < 2; ++j) {
    const int o = o0 + 32 * wo + 16 * j + lx;
    const float bias = bo[o];
#pragma unroll
    for (int i = 0; i < 2; ++i) {
      const int n = n0 + 32 * wn + 16 * i + 4 * q;
      const float4 xv = *(const float4*)(x + ((size_t)(b * CIN_ + o)) * NTOK_ + n);
      float4 v;
      v.x = fmaxf(acc[i][j][0] + bias, 0.f) + xv.x;
      v.y = fmaxf(acc[i][j][1] + bias, 0.f) + xv.y;
      v.z = fmaxf(acc[i][j][2] + bias, 0.f) + xv.z;
      v.w = fmaxf(acc[i][j][3] + bias, 0.f) + xv.w;
      *(float4*)(pre + ((size_t)(b * COUT_ + o)) * NTOK_ + n) = v;
      s[j] += v.x + v.y + v.z + v.w;
      s2[j] += v.x * v.x + v.y * v.y + v.z * v.z + v.w * v.w;
    }
  }
#pragma unroll
  for (int j = 0; j < 2; ++j) {
    s[j] += __shfl_xor(s[j], 16);  s[j] += __shfl_xor(s[j], 32);
    s2[j] += __shfl_xor(s2[j], 16); s2[j] += __shfl_xor(s2[j], 32);
  }
  if (lane < 16) {
#pragma unroll
    for (int j = 0; j < 2; ++j) {
      const int o = o0 + 32 * wo + 16 * j + lx;
      atomicAdd(&stats[o], s[j]);
      atomicAdd(&stats[COUT_ + o], s2[j]);
    }
  }
}

// ---------------------------------------------------------------------------
// Kernel 4: BatchNorm finalize, in place on d_out.
// ---------------------------------------------------------------------------
__global__ __launch_bounds__(256) void bn_kernel(
    float* __restrict__ out, const float* __restrict__ stats,
    const float* __restrict__ gamma, const float* __restrict__ beta) {
  const int idx = blockIdx.x * 256 + threadIdx.x;
  const int e = idx * 4;
  const int c = (e >> 11) & (COUT_ - 1);
  const float inv = 1.0f / (float)(BB_ * NTOK_);
  const float mean = stats[c] * inv;
  const float var = stats[COUT_ + c] * inv - mean * mean;
  const float sc = rsqrtf(var + BNEPS_) * gamma[c];
  const float bt = beta[c];
  float4 v = *(float4*)(out + e);
  v.x = (v.x - mean) * sc + bt;
  v.y = (v.y - mean) * sc + bt;
  v.z = (v.z - mean) * sc + bt;
  v.w = (v.w - mean) * sc + bt;
  *(float4*)(out + e) = v;
}

extern "C" void kernel_launch(void* const* d_in, const int* in_sizes, int n_in,
                              void* d_out, int out_size, void* d_ws, size_t ws_size,
                              hipStream_t stream) {
  (void)in_sizes; (void)n_in; (void)out_size; (void)ws_size;
  const float* x = (const float*)d_in[0];
  const float* WK = (const float*)d_in[1];
  const float* WQ = (const float*)d_in[2];
  const float* WV = (const float*)d_in[3];
  const float* Wo = (const float*)d_in[4];
  const float* bo = (const float*)d_in[5];
  const float* gamma = (const float*)d_in[6];
  const float* beta = (const float*)d_in[7];

  char* ws = (char*)d_ws;
  unsigned short* xT  = (unsigned short*)(ws);                    // 2 MB
  unsigned short* Wkb = (unsigned short*)(ws + 2097152);          // 256 KB x4
  unsigned short* Wqb = (unsigned short*)(ws + 2359296);
  unsigned short* Wvb = (unsigned short*)(ws + 2621440);
  unsigned short* Wob = (unsigned short*)(ws + 2883584);
  unsigned short* Kb  = (unsigned short*)(ws + 3145728);          // 4 MB
  unsigned short* Qb  = (unsigned short*)(ws + 7340032);          // 4 MB
  unsigned short* Vt  = (unsigned short*)(ws + 11534336);         // 4 MB
  unsigned short* Ob  = (unsigned short*)(ws + 15728640);         // 4 MB
  float* stats        = (float*)(ws + 19922944);                  // 2 KB
  float* out = (float*)d_out;

  prep_kernel<<<385, 256, 0, stream>>>(x, WK, WQ, WV, Wo, xT, Wkb, Wqb, Wvb, Wob, stats);
  qkv_kernel<<<dim3(16, 4, 6), 256, 0, stream>>>(xT, Wkb, Wqb, Wvb, Kb, Qb, Vt);
  attn_kernel<<<dim3(512, 1, 1), 256, 0, stream>>>(Kb, Qb, Vt, Ob);
  proj_kernel<<<dim3(32, 4, 2), 256, 0, stream>>>(Ob, Wob, bo, x, out, stats);
  bn_kernel<<<1024, 256, 0, stream>>>(out, stats, gamma, beta);
}

// Round 7
// 150.559 us; speedup vs baseline: 1.3512x; 1.1923x over previous
//
#include <hip/hip_runtime.h>
#include <math.h>

#define BB_   2
#define CIN_  256
#define NTOK_ 2048
#define FF_   512
#define COUT_ 256
#define NH_   8
#define DH_   64
#define HW_   128
#define BNEPS_ 1e-5f
#define SCALE_LOG2_ 0.09016844005556021f  /* log2(e)/16 */

typedef __attribute__((ext_vector_type(8))) short short8;
typedef __attribute__((ext_vector_type(4))) float f32x4;

__device__ inline unsigned short f2bf(float f) {
  union { float f; unsigned u; } v; v.f = f;
  unsigned r = (v.u + 0x7FFF + ((v.u >> 16) & 1)) >> 16;  // RNE
  return (unsigned short)r;
}
__device__ inline float bf2f(unsigned short u) {
  union { unsigned u; float f; } v; v.u = ((unsigned)u) << 16;
  return v.f;
}

// async global->LDS DMA, 16 B per lane; LDS dest = wave-uniform base + lane*16
__device__ __forceinline__ void dma16(const unsigned short* g, unsigned short* l) {
  __builtin_amdgcn_global_load_lds(
      (const __attribute__((address_space(1))) void*)g,
      (__attribute__((address_space(3))) void*)l, 16, 0, 0);
}

// ---------------------------------------------------------------------------
// Kernel 0: prep — x fp32 [b][c][n] -> xT bf16 [b][n][c] (LDS transpose);
// weights fp32 -> bf16 flat; zero BN stats.
// ---------------------------------------------------------------------------
__global__ __launch_bounds__(256) void prep_kernel(
    const float* __restrict__ x, const float* __restrict__ WK,
    const float* __restrict__ WQ, const float* __restrict__ WV,
    const float* __restrict__ Wo, unsigned short* __restrict__ xT,
    unsigned short* __restrict__ Wkb, unsigned short* __restrict__ Wqb,
    unsigned short* __restrict__ Wvb, unsigned short* __restrict__ Wob,
    float* __restrict__ stats) {
  __shared__ float T[64 * 65];
  const int tid = threadIdx.x;
  const int bid = blockIdx.x;
  if (bid < 256) {
    const int b = bid >> 7;
    const int rem = bid & 127;
    const int n0 = (rem >> 2) * 64;
    const int c0 = (rem & 3) * 64;
#pragma unroll
    for (int p = 0; p < 4; ++p) {
      const int idx = tid + 256 * p;
      const int row = idx >> 4, col = (idx & 15) * 4;
      const float4 v =
          *(const float4*)(x + (size_t)(b * CIN_ + c0 + row) * NTOK_ + n0 + col);
      T[row * 65 + col + 0] = v.x; T[row * 65 + col + 1] = v.y;
      T[row * 65 + col + 2] = v.z; T[row * 65 + col + 3] = v.w;
    }
    __syncthreads();
#pragma unroll
    for (int p = 0; p < 2; ++p) {
      const int idx = tid + 256 * p;
      const int nl = idx >> 3, c8 = (idx & 7) * 8;
      unsigned short u[8];
#pragma unroll
      for (int i = 0; i < 8; ++i) u[i] = f2bf(T[(c8 + i) * 65 + nl]);
      *(uint4*)(xT + ((size_t)(b * NTOK_ + n0 + nl)) * CIN_ + c0 + c8) =
          *(uint4*)u;
    }
  } else if (bid < 384) {
    const int t = bid - 256;
    const int which = t >> 5, blk = t & 31;
    const float* src = which == 0 ? WK : which == 1 ? WQ : which == 2 ? WV : Wo;
    unsigned short* dst = which == 0 ? Wkb : which == 1 ? Wqb : which == 2 ? Wvb : Wob;
    const int base = blk * 4096 + tid * 16;
#pragma unroll
    for (int p = 0; p < 4; ++p) {
      const float4 v = *(const float4*)(src + base + p * 4);
      ushort4 u;
      u.x = f2bf(v.x); u.y = f2bf(v.y); u.z = f2bf(v.z); u.w = f2bf(v.w);
      *(ushort4*)(dst + base + p * 4) = u;
    }
  } else {
    for (int i = tid; i < 2 * COUT_; i += 256) stats[i] = 0.f;
  }
}

// ---------------------------------------------------------------------------
// Kernel 1: QKV projection via MFMA. 128f x 128n tile, 4 waves.
// K,Q -> [b][h][n][d] bf16; V (operand-swapped) -> [b][h][d][n] bf16.
// ---------------------------------------------------------------------------
__global__ __launch_bounds__(256, 2) void qkv_kernel(
    const unsigned short* __restrict__ xT, const unsigned short* __restrict__ Wkb,
    const unsigned short* __restrict__ Wqb, const unsigned short* __restrict__ Wvb,
    unsigned short* __restrict__ Kb, unsigned short* __restrict__ Qb,
    unsigned short* __restrict__ Vt) {
  __shared__ unsigned short Wsh[128 * 72];
  __shared__ unsigned short Xsh[128 * 72];
  const int tid = threadIdx.x;
  const int lane = tid & 63, w = tid >> 6;
  const int lx = lane & 15, q = lane >> 4;
  const int wm = w >> 1, wn = w & 1;
  const int n0 = blockIdx.x * 128;
  const int f0 = blockIdx.y * 128;
  const int b = blockIdx.z / 3, which = blockIdx.z % 3;
  const unsigned short* Wb = which == 0 ? Wkb : which == 1 ? Wqb : Wvb;

  const int srow = tid >> 3;
  const int soff = (tid & 7) * 8;
  const unsigned short* Wg = Wb + (size_t)(f0 + srow) * CIN_ + soff;
  const unsigned short* Xg = xT + ((size_t)(b * NTOK_ + n0 + srow)) * CIN_ + soff;

  uint4 wr[4], xr[4];
#pragma unroll
  for (int r = 0; r < 4; ++r) {
    wr[r] = *(const uint4*)(Wg + (size_t)(32 * r) * CIN_);
    xr[r] = *(const uint4*)(Xg + (size_t)(32 * r) * CIN_);
  }

  f32x4 acc[4][4];
#pragma unroll
  for (int i = 0; i < 4; ++i)
#pragma unroll
    for (int j = 0; j < 4; ++j) acc[i][j] = (f32x4){0.f, 0.f, 0.f, 0.f};

  for (int kk = 0; kk < 4; ++kk) {
    __syncthreads();
#pragma unroll
    for (int r = 0; r < 4; ++r) {
      *(uint4*)(Wsh + (srow + 32 * r) * 72 + soff) = wr[r];
      *(uint4*)(Xsh + (srow + 32 * r) * 72 + soff) = xr[r];
    }
    if (kk < 3) {
      const int c0 = (kk + 1) * 64;
#pragma unroll
      for (int r = 0; r < 4; ++r) {
        wr[r] = *(const uint4*)(Wg + (size_t)(32 * r) * CIN_ + c0);
        xr[r] = *(const uint4*)(Xg + (size_t)(32 * r) * CIN_ + c0);
      }
    }
    __syncthreads();
    short8 xF[4][2];
#pragma unroll
    for (int i = 0; i < 4; ++i) {
      xF[i][0] = *(const short8*)(Xsh + (64 * wn + 16 * i + lx) * 72 + q * 8);
      xF[i][1] = *(const short8*)(Xsh + (64 * wn + 16 * i + lx) * 72 + 32 + q * 8);
    }
    if (which < 2) {
#pragma unroll
      for (int i = 0; i < 4; ++i) {
        const short8 w0 = *(const short8*)(Wsh + (64 * wm + 16 * i + lx) * 72 + q * 8);
        const short8 w1 = *(const short8*)(Wsh + (64 * wm + 16 * i + lx) * 72 + 32 + q * 8);
#pragma unroll
        for (int j = 0; j < 4; ++j) {
          acc[i][j] = __builtin_amdgcn_mfma_f32_16x16x32_bf16(w0, xF[j][0], acc[i][j], 0, 0, 0);
          acc[i][j] = __builtin_amdgcn_mfma_f32_16x16x32_bf16(w1, xF[j][1], acc[i][j], 0, 0, 0);
        }
      }
    } else {
#pragma unroll
      for (int j = 0; j < 4; ++j) {
        const short8 w0 = *(const short8*)(Wsh + (64 * wm + 16 * j + lx) * 72 + q * 8);
        const short8 w1 = *(const short8*)(Wsh + (64 * wm + 16 * j + lx) * 72 + 32 + q * 8);
#pragma unroll
        for (int i = 0; i < 4; ++i) {
          acc[i][j] = __builtin_amdgcn_mfma_f32_16x16x32_bf16(xF[i][0], w0, acc[i][j], 0, 0, 0);
          acc[i][j] = __builtin_amdgcn_mfma_f32_16x16x32_bf16(xF[i][1], w1, acc[i][j], 0, 0, 0);
        }
      }
    }
  }

  const int h = (f0 >> 6) + wm;
  if (which < 2) {
    unsigned short* Y = (which == 0 ? Kb : Qb);
#pragma unroll
    for (int i = 0; i < 4; ++i)
#pragma unroll
      for (int j = 0; j < 4; ++j) {
        const int n = n0 + 64 * wn + 16 * j + lx;
        const int d0 = 16 * i + 4 * q;
        ushort4 u;
        u.x = f2bf(acc[i][j][0]); u.y = f2bf(acc[i][j][1]);
        u.z = f2bf(acc[i][j][2]); u.w = f2bf(acc[i][j][3]);
        *(ushort4*)(Y + ((size_t)((b * NH_ + h) * NTOK_ + n)) * DH_ + d0) = u;
      }
  } else {
#pragma unroll
    for (int i = 0; i < 4; ++i)
#pragma unroll
      for (int j = 0; j < 4; ++j) {
        const int d = 16 * j + lx;
        const int n = n0 + 64 * wn + 16 * i + 4 * q;
        ushort4 u;
        u.x = f2bf(acc[i][j][0]); u.y = f2bf(acc[i][j][1]);
        u.z = f2bf(acc[i][j][2]); u.w = f2bf(acc[i][j][3]);
        *(ushort4*)(Vt + ((size_t)((b * NH_ + h) * DH_ + d)) * NTOK_ + n) = u;
      }
  }
}

// ---------------------------------------------------------------------------
// Kernel 2: block-causal attention — async-DMA double-buffered Q/V staging.
// global_load_lds (16B/lane) stages tile jt+1 while tile jt computes; the
// vmcnt(0) drain inside __syncthreads() at iteration end synchronizes.
// DMA LDS dest is forced-linear, so the GLOBAL source address is swizzled:
// LDS slot (row, chunk) <- G(row, chunk ^ (row&7)); frag reads XOR the same
// -> b128 LDS reads are 2-way on banks (free). Wave-private P transpose,
// unshifted exp2 softmax (scores bounded), LPT block pairing, XCD<->head.
// ---------------------------------------------------------------------------
__global__ __launch_bounds__(256, 2) void attn_kernel(
    const unsigned short* __restrict__ Kb, const unsigned short* __restrict__ Qb,
    const unsigned short* __restrict__ Vt, unsigned short* __restrict__ Ob) {
  __shared__ __align__(16) unsigned short Qbuf[2][4096];   // [j(64)][d(64)] swizzled
  __shared__ __align__(16) unsigned short Vbuf[2][4096];   // [d(64)][j(64)] swizzled
  __shared__ __align__(16) unsigned short Psh[4 * 16 * 72];

  const int tid = threadIdx.x;
  const int lane = tid & 63;
  const int w = tid >> 6;
  const int lx = lane & 15;
  const int q = lane >> 4;

  const int bid = blockIdx.x;      // 0..511
  const int u = bid >> 4;
  const int iblk = (u < 16) ? (31 - u) : (u - 16);   // LPT pairing
  const int bh = bid & 15;
  const int h = bh & 7, b = bh >> 3;
  const int i0 = iblk * 64;
  const int njt = ((iblk >> 1) + 1) * 2;   // always even

  const size_t bhs = (size_t)b * NH_ + h;
  const unsigned short* Kg = Kb + bhs * (size_t)NTOK_ * DH_ + (size_t)i0 * DH_;
  const unsigned short* Qg = Qb + bhs * (size_t)NTOK_ * DH_;
  const unsigned short* Vg = Vt + bhs * (size_t)DH_ * NTOK_;

  // per-lane DMA source geometry: this lane fills LDS slot (row, c) of its
  // wave's chunks; source column-chunk is c ^ (row&7).
  const int drow_lo = (lane >> 3);        // row offset within a 1KB chunk (8 rows)
  const int dcg = (lane & 7) ^ drow_lo;   // swizzled source chunk (row&7 == drow_lo)

  // wave w stages chunks {2w, 2w+1} of both Q and V tiles (4 dma16 calls)
  auto stage = [&](int buf, int j0) {
#pragma unroll
    for (int cc = 0; cc < 2; ++cc) {
      const int chunk = 2 * w + cc;
      const int row = chunk * 8 + drow_lo;
      dma16(Qg + (size_t)(j0 + row) * DH_ + dcg * 8, &Qbuf[buf][chunk * 512]);
      dma16(Vg + (size_t)row * NTOK_ + j0 + dcg * 8, &Vbuf[buf][chunk * 512]);
    }
  };

  // K A-frags straight from global (one-time): token row i0+16w+lx
  const short8 aK0 = *(const short8*)(Kg + (16 * w + lx) * DH_ + q * 8);
  const short8 aK1 = *(const short8*)(Kg + (16 * w + lx) * DH_ + 32 + q * 8);

  unsigned short* Pw = Psh + w * 16 * 72;

  f32x4 o[4];      // O^T accum: row d=16s+4q+r, col i=lx (token i0+16w+lx)
#pragma unroll
  for (int s = 0; s < 4; ++s) o[s] = (f32x4){0.f, 0.f, 0.f, 0.f};
  float rsum[4] = {0.f, 0.f, 0.f, 0.f};

  // frag-read swizzled chunk offsets (elements): frag0 chunk q, frag1 chunk 4+q
  const int fr0 = ((q ^ (lx & 7)) << 3);
  const int fr1 = (((4 + q) ^ (lx & 7)) << 3);

  stage(0, 0);
  __syncthreads();   // drains DMA (vmcnt0)

  int cur = 0;
  for (int jt = 0; jt < njt; ++jt) {
    if (jt + 1 < njt) stage(cur ^ 1, (jt + 1) * 64);  // DMA overlaps compute

    const unsigned short* Qs = Qbuf[cur];
    const unsigned short* Vs = Vbuf[cur];

    // S-phase: S[16i x 64j] (row i=4q+r local, col j=16s+lx)
    f32x4 sa[4];
#pragma unroll
    for (int s = 0; s < 4; ++s) {
      const int row = 16 * s + lx;
      const short8 b0 = *(const short8*)(Qs + row * 64 + fr0);
      const short8 b1 = *(const short8*)(Qs + row * 64 + fr1);
      sa[s] = (f32x4){0.f, 0.f, 0.f, 0.f};
      sa[s] = __builtin_amdgcn_mfma_f32_16x16x32_bf16(aK0, b0, sa[s], 0, 0, 0);
      sa[s] = __builtin_amdgcn_mfma_f32_16x16x32_bf16(aK1, b1, sa[s], 0, 0, 0);
    }

    // unshifted exponentials; per-lane row-sum partials; P -> wave-private LDS
#pragma unroll
    for (int s = 0; s < 4; ++s)
#pragma unroll
      for (int r = 0; r < 4; ++r) {
        const float p = __builtin_amdgcn_exp2f(sa[s][r] * SCALE_LOG2_);
        rsum[r] += p;
        Pw[(q * 4 + r) * 72 + 16 * s + lx] = f2bf(p);
      }
    asm volatile("s_waitcnt lgkmcnt(0)" ::: "memory");  // own-wave P visible

    // PV^T: O^T[64d x 16i] += V^T[64d x 64j] * P^T[64j x 16i]
    const short8 pb0 = *(const short8*)(Pw + lx * 72 + q * 8);
    const short8 pb1 = *(const short8*)(Pw + lx * 72 + 32 + q * 8);
#pragma unroll
    for (int s = 0; s < 4; ++s) {
      const int row = 16 * s + lx;
      const short8 va0 = *(const short8*)(Vs + row * 64 + fr0);
      const short8 va1 = *(const short8*)(Vs + row * 64 + fr1);
      o[s] = __builtin_amdgcn_mfma_f32_16x16x32_bf16(va0, pb0, o[s], 0, 0, 0);
      o[s] = __builtin_amdgcn_mfma_f32_16x16x32_bf16(va1, pb1, o[s], 0, 0, 0);
    }

    __syncthreads();   // drains next-tile DMA; guards double-buffer reuse
    cur ^= 1;
  }

  // reduce row sums across the 16 lanes of each q-group (once per block)
#pragma unroll
  for (int r = 0; r < 4; ++r) {
#pragma unroll
    for (int off = 1; off < 16; off <<= 1) rsum[r] += __shfl_xor(rsum[r], off);
  }
  const int gsrc = ((lx >> 2) << 4);
  const float u0 = __shfl(rsum[0], gsrc);
  const float u1 = __shfl(rsum[1], gsrc);
  const float u2 = __shfl(rsum[2], gsrc);
  const float u3 = __shfl(rsum[3], gsrc);
  const float lsel = (lx & 2) ? ((lx & 1) ? u3 : u2) : ((lx & 1) ? u1 : u0);
  const float invl = 1.0f / lsel;
  const int n = i0 + 16 * w + lx;
#pragma unroll
  for (int s = 0; s < 4; ++s) {
    ushort4 uo;
    uo.x = f2bf(o[s][0] * invl); uo.y = f2bf(o[s][1] * invl);
    uo.z = f2bf(o[s][2] * invl); uo.w = f2bf(o[s][3] * invl);
    *(ushort4*)(Ob + ((size_t)(b * NTOK_ + n)) * FF_ + h * 64 + 16 * s + 4 * q) = uo;
  }
}

// ---------------------------------------------------------------------------
// Kernel 3: output projection via MFMA + bias + ReLU + skip -> d_out fp32,
// + BN stats (shuffle-reduced atomics).
// ---------------------------------------------------------------------------
__global__ __launch_bounds__(256) void proj_kernel(
    const unsigned short* __restrict__ Ob, const unsigned short* __restrict__ Wob,
    const float* __restrict__ bo, const float* __restrict__ x,
    float* __restrict__ pre, float* __restrict__ stats) {
  __shared__ unsigned short Osh[64 * 72];
  __shared__ unsigned short Wsh[64 * 72];
  const int tid = threadIdx.x;
  const int lane = tid & 63, w = tid >> 6;
  const int lx = lane & 15, q = lane >> 4;
  const int wn = w & 1, wo = w >> 1;
  const int n0 = blockIdx.x * 64;
  const int o0 = blockIdx.y * 64;
  const int b = blockIdx.z;

  const int srow = tid >> 3;
  const int soff = (tid & 7) * 8;
  const unsigned short* Og = Ob + ((size_t)(b * NTOK_ + n0 + srow)) * FF_ + soff;
  const unsigned short* Wg = Wob + (size_t)(o0 + srow) * FF_ + soff;

  uint4 orr[2], wrr[2];
#pragma unroll
  for (int r = 0; r < 2; ++r) {
    orr[r] = *(const uint4*)(Og + (size_t)(32 * r) * FF_);
    wrr[r] = *(const uint4*)(Wg + (size_t)(32 * r) * FF_);
  }

  f32x4 acc[2][2];
#pragma unroll
  for (int i = 0; i < 2; ++i)
#pragma unroll
    for (int j = 0; j < 2; ++j) acc[i][j] = (f32x4){0.f, 0.f, 0.f, 0.f};

  for (int kk = 0; kk < 8; ++kk) {
    __syncthreads();
#pragma unroll
    for (int r = 0; r < 2; ++r) {
      *(uint4*)(Osh + (srow + 32 * r) * 72 + soff) = orr[r];
      *(uint4*)(Wsh + (srow + 32 * r) * 72 + soff) = wrr[r];
    }
    if (kk < 7) {
      const int c0 = (kk + 1) * 64;
#pragma unroll
      for (int r = 0; r < 2; ++r) {
        orr[r] = *(const uint4*)(Og + (size_t)(32 * r) * FF_ + c0);
        wrr[r] = *(const uint4*)(Wg + (size_t)(32 * r) * FF_ + c0);
      }
    }
    __syncthreads();
    short8 aF[2][2], bF[2][2];
#pragma unroll
    for (int i = 0; i < 2; ++i) {
      aF[i][0] = *(const short8*)(Osh + (32 * wn + 16 * i + lx) * 72 + q * 8);
      aF[i][1] = *(const short8*)(Osh + (32 * wn + 16 * i + lx) * 72 + 32 + q * 8);
      bF[i][0] = *(const short8*)(Wsh + (32 * wo + 16 * i + lx) * 72 + q * 8);
      bF[i][1] = *(const short8*)(Wsh + (32 * wo + 16 * i + lx) * 72 + 32 + q * 8);
    }
#pragma unroll
    for (int i = 0; i < 2; ++i)
#pragma unroll
      for (int j = 0; j < 2; ++j) {
        acc[i][j] = __builtin_amdgcn_mfma_f32_16x16x32_bf16(aF[i][0], bF[j][0], acc[i][j], 0, 0, 0);
        acc[i][j] = __builtin_amdgcn_mfma_f32_16x16x32_bf16(aF[i][1], bF[j][1], acc[i][j], 0, 0, 0);
      }
  }

  float s[2] = {0.f, 0.f}, s2[2] = {0.f, 0.f};
#pragma unroll
  for (int j = 0; j < 2; ++j) {
    const int o = o0 + 32 * wo + 16 * j + lx;
    const float bias = bo[o];
#pragma unroll
    for (int i = 0; i < 2; ++i) {
      const int n = n0 + 32 * wn + 16 * i + 4 * q;
      const float4 xv = *(const float4*)(x + ((size_t)(b * CIN_ + o)) * NTOK_ + n);
      float4 v;
      v.x = fmaxf(acc[i][j][0] + bias, 0.f) + xv.x;
      v.y = fmaxf(acc[i][j][1] + bias, 0.f) + xv.y;
      v.z = fmaxf(acc[i][j][2] + bias, 0.f) + xv.z;
      v.w = fmaxf(acc[i][j][3] + bias, 0.f) + xv.w;
      *(float4*)(pre + ((size_t)(b * COUT_ + o)) * NTOK_ + n) = v;
      s[j] += v.x + v.y + v.z + v.w;
      s2[j] += v.x * v.x + v.y * v.y + v.z * v.z + v.w * v.w;
    }
  }
#pragma unroll
  for (int j = 0; j < 2; ++j) {
    s[j] += __shfl_xor(s[j], 16);  s[j] += __shfl_xor(s[j], 32);
    s2[j] += __shfl_xor(s2[j], 16); s2[j] += __shfl_xor(s2[j], 32);
  }
  if (lane < 16) {
#pragma unroll
    for (int j = 0; j < 2; ++j) {
      const int o = o0 + 32 * wo + 16 * j + lx;
      atomicAdd(&stats[o], s[j]);
      atomicAdd(&stats[COUT_ + o], s2[j]);
    }
  }
}

// ---------------------------------------------------------------------------
// Kernel 4: BatchNorm finalize, in place on d_out.
// ---------------------------------------------------------------------------
__global__ __launch_bounds__(256) void bn_kernel(
    float* __restrict__ out, const float* __restrict__ stats,
    const float* __restrict__ gamma, const float* __restrict__ beta) {
  const int idx = blockIdx.x * 256 + threadIdx.x;
  const int e = idx * 4;
  const int c = (e >> 11) & (COUT_ - 1);
  const float inv = 1.0f / (float)(BB_ * NTOK_);
  const float mean = stats[c] * inv;
  const float var = stats[COUT_ + c] * inv - mean * mean;
  const float sc = rsqrtf(var + BNEPS_) * gamma[c];
  const float bt = beta[c];
  float4 v = *(float4*)(out + e);
  v.x = (v.x - mean) * sc + bt;
  v.y = (v.y - mean) * sc + bt;
  v.z = (v.z - mean) * sc + bt;
  v.w = (v.w - mean) * sc + bt;
  *(float4*)(out + e) = v;
}

extern "C" void kernel_launch(void* const* d_in, const int* in_sizes, int n_in,
                              void* d_out, int out_size, void* d_ws, size_t ws_size,
                              hipStream_t stream) {
  (void)in_sizes; (void)n_in; (void)out_size; (void)ws_size;
  const float* x = (const float*)d_in[0];
  const float* WK = (const float*)d_in[1];
  const float* WQ = (const float*)d_in[2];
  const float* WV = (const float*)d_in[3];
  const float* Wo = (const float*)d_in[4];
  const float* bo = (const float*)d_in[5];
  const float* gamma = (const float*)d_in[6];
  const float* beta = (const float*)d_in[7];

  char* ws = (char*)d_ws;
  unsigned short* xT  = (unsigned short*)(ws);                    // 2 MB
  unsigned short* Wkb = (unsigned short*)(ws + 2097152);          // 256 KB x4
  unsigned short* Wqb = (unsigned short*)(ws + 2359296);
  unsigned short* Wvb = (unsigned short*)(ws + 2621440);
  unsigned short* Wob = (unsigned short*)(ws + 2883584);
  unsigned short* Kb  = (unsigned short*)(ws + 3145728);          // 4 MB
  unsigned short* Qb  = (unsigned short*)(ws + 7340032);          // 4 MB
  unsigned short* Vt  = (unsigned short*)(ws + 11534336);         // 4 MB
  unsigned short* Ob  = (unsigned short*)(ws + 15728640);         // 4 MB
  float* stats        = (float*)(ws + 19922944);                  // 2 KB
  float* out = (float*)d_out;

  prep_kernel<<<385, 256, 0, stream>>>(x, WK, WQ, WV, Wo, xT, Wkb, Wqb, Wvb, Wob, stats);
  qkv_kernel<<<dim3(16, 4, 6), 256, 0, stream>>>(xT, Wkb, Wqb, Wvb, Kb, Qb, Vt);
  attn_kernel<<<dim3(512, 1, 1), 256, 0, stream>>>(Kb, Qb, Vt, Ob);
  proj_kernel<<<dim3(32, 4, 2), 256, 0, stream>>>(Ob, Wob, bo, x, out, stats);
  bn_kernel<<<1024, 256, 0, stream>>>(out, stats, gamma, beta);
}